// Round 1
// baseline (798.789 us; speedup 1.0000x reference)
//
#include <hip/hip_runtime.h>
#include <math.h>

// MoE router: N=16384 tokens, D=4096, E=64 experts, top-8.
// Kernel 1: logits = (x * (0.99 + 0.02*noise)) @ W   -- f32 GEMM, memory-bound
// Kernel 2: softmax -> biased top-8 (tie: lower index) -> L2-normalized weights
//           -> histogram (float counts, since d_out is one flat f32 buffer)

#define N_TOK 16384
#define DIM   4096
#define NEXP  64
#define TOPK  8

#define BM 64
#define BK 64
#define NCHUNK (DIM / BK)   // 64
#define XS_STRIDE 68        // 64 + 4 pad (keeps 16B alignment, breaks bank aliasing)

__global__ __launch_bounds__(256) void gemm_logits_kernel(
    const float* __restrict__ x, const float* __restrict__ W,
    const float* __restrict__ noise, float* __restrict__ logits)
{
    __shared__ float xs[BM * XS_STRIDE];  // 17408 B, jittered x tile
    __shared__ float ws[BK * NEXP];       // 16384 B, W tile (d-major, stride 64)

    const int t = threadIdx.x;
    const int rowBase = blockIdx.x * BM;
    const int eg = t & 15;   // expert group -> experts eg*4 .. eg*4+3
    const int rg = t >> 4;   // row group    -> rows    rg*4 .. rg*4+3

    float acc[4][4];
#pragma unroll
    for (int m = 0; m < 4; ++m)
#pragma unroll
        for (int n = 0; n < 4; ++n) acc[m][n] = 0.0f;

    // register prefetch buffers (next K-chunk): overlaps HBM with compute,
    // essential at 1 block/CU where a bare load->barrier->compute serializes.
    float4 px[4], pn[4], pw[4];

    // preload chunk 0
#pragma unroll
    for (int i = 0; i < 4; ++i) {
        const int f  = t + i * 256;          // float4 index within 64x16-f4 tile
        const int r  = f >> 4;
        const int c4 = f & 15;
        const size_t g = (size_t)(rowBase + r) * DIM + (size_t)(c4 * 4);
        px[i] = *(const float4*)(x + g);
        pn[i] = *(const float4*)(noise + g);
        pw[i] = *(const float4*)(W + (size_t)f * 4);
    }

    for (int kt = 0; kt < NCHUNK; ++kt) {
        __syncthreads();  // previous chunk's readers done
        // stage prefetched regs -> LDS (apply jitter here)
#pragma unroll
        for (int i = 0; i < 4; ++i) {
            const int f  = t + i * 256;
            const int r  = f >> 4;
            const int c4 = f & 15;
            const float4 xv = px[i], nv = pn[i];
            float4 j;
            j.x = xv.x * (0.99f + 0.02f * nv.x);
            j.y = xv.y * (0.99f + 0.02f * nv.y);
            j.z = xv.z * (0.99f + 0.02f * nv.z);
            j.w = xv.w * (0.99f + 0.02f * nv.w);
            *(float4*)&xs[r * XS_STRIDE + c4 * 4] = j;
            *(float4*)&ws[f * 4] = pw[i];
        }
        __syncthreads();

        // issue next chunk's global loads before computing (latency hidden by FMAs)
        if (kt + 1 < NCHUNK) {
            const int k0 = (kt + 1) * BK;
#pragma unroll
            for (int i = 0; i < 4; ++i) {
                const int f  = t + i * 256;
                const int r  = f >> 4;
                const int c4 = f & 15;
                const size_t g = (size_t)(rowBase + r) * DIM + (size_t)(k0 + c4 * 4);
                px[i] = *(const float4*)(x + g);
                pn[i] = *(const float4*)(noise + g);
                pw[i] = *(const float4*)(W + (size_t)(kt + 1) * BK * NEXP + (size_t)f * 4);
            }
        }

        // compute: 64 kk steps, 4x4 register tile
        const float4* xs4 = (const float4*)xs;   // row stride = 17 float4
        const float4* ws4 = (const float4*)ws;   // kk stride  = 16 float4
#pragma unroll 4
        for (int kk4 = 0; kk4 < 16; ++kk4) {
            const float4 b0 = ws4[(kk4 * 4 + 0) * 16 + eg];
            const float4 b1 = ws4[(kk4 * 4 + 1) * 16 + eg];
            const float4 b2 = ws4[(kk4 * 4 + 2) * 16 + eg];
            const float4 b3 = ws4[(kk4 * 4 + 3) * 16 + eg];
#pragma unroll
            for (int m = 0; m < 4; ++m) {
                const float4 a = xs4[(rg * 4 + m) * 17 + kk4];
                acc[m][0] += a.x * b0.x; acc[m][1] += a.x * b0.y;
                acc[m][2] += a.x * b0.z; acc[m][3] += a.x * b0.w;
                acc[m][0] += a.y * b1.x; acc[m][1] += a.y * b1.y;
                acc[m][2] += a.y * b1.z; acc[m][3] += a.y * b1.w;
                acc[m][0] += a.z * b2.x; acc[m][1] += a.z * b2.y;
                acc[m][2] += a.z * b2.z; acc[m][3] += a.z * b2.w;
                acc[m][0] += a.w * b3.x; acc[m][1] += a.w * b3.y;
                acc[m][2] += a.w * b3.z; acc[m][3] += a.w * b3.w;
            }
        }
    }

    // epilogue: write logits
#pragma unroll
    for (int m = 0; m < 4; ++m) {
        float4 o;
        o.x = acc[m][0]; o.y = acc[m][1]; o.z = acc[m][2]; o.w = acc[m][3];
        *(float4*)(logits + (size_t)(rowBase + rg * 4 + m) * NEXP + eg * 4) = o;
    }
}

__global__ __launch_bounds__(256) void router_topk_kernel(
    const float* __restrict__ logits, const float* __restrict__ score_bias,
    float* __restrict__ scores, float* __restrict__ weights,
    float* __restrict__ indicesF, float* __restrict__ histF)
{
    __shared__ int hist[NEXP];
    const int t = threadIdx.x;
    if (t < NEXP) hist[t] = 0;
    __syncthreads();

    const int lane = t & 63;
    const int w    = t >> 6;            // wave id 0..3
    const float bias = score_bias[lane];
    const int base = blockIdx.x * 64;   // 64 rows per block, 256 blocks

    for (int it = 0; it < 16; ++it) {
        const int row = base + it * 4 + w;
        const float lg = logits[(size_t)row * NEXP + lane];

        // softmax (wave butterfly reductions over 64 lanes)
        float mx = lg;
#pragma unroll
        for (int off = 32; off > 0; off >>= 1)
            mx = fmaxf(mx, __shfl_xor(mx, off));
        const float p = expf(lg - mx);
        float s = p;
#pragma unroll
        for (int off = 32; off > 0; off >>= 1)
            s += __shfl_xor(s, off);
        const float sc = p / s;
        scores[(size_t)row * NEXP + lane] = sc;

        // biased top-8, tie -> lower index (jax.lax.top_k semantics)
        float v = sc + bias;
        int myIdx = 0; float myW = 0.0f;
        float ssq = 0.0f;
#pragma unroll
        for (int k = 0; k < TOPK; ++k) {
            float bv = v; int bi = lane;
#pragma unroll
            for (int off = 32; off > 0; off >>= 1) {
                const float ov = __shfl_xor(bv, off);
                const int   oi = __shfl_xor(bi, off);
                if (ov > bv || (ov == bv && oi < bi)) { bv = ov; bi = oi; }
            }
            // all lanes now hold the argmax (bi); gather unbiased score
            const float wk = __shfl(sc, bi);
            ssq += wk * wk;
            if (lane == k)  { myIdx = bi; myW = wk; }
            if (lane == bi) v = -INFINITY;
        }

        if (lane < TOPK) {
            const float norm = sqrtf(ssq);
            weights[(size_t)row * TOPK + lane]  = myW / norm;
            indicesF[(size_t)row * TOPK + lane] = (float)myIdx;  // d_out is flat f32
            atomicAdd(&hist[myIdx], 1);
        }
    }

    __syncthreads();
    if (t < NEXP) atomicAdd(&histF[t], (float)hist[t]);
}

extern "C" void kernel_launch(void* const* d_in, const int* in_sizes, int n_in,
                              void* d_out, int out_size, void* d_ws, size_t ws_size,
                              hipStream_t stream)
{
    const float* x     = (const float*)d_in[0];
    const float* W     = (const float*)d_in[1];
    const float* sbias = (const float*)d_in[2];
    const float* noise = (const float*)d_in[3];

    float* out      = (float*)d_out;
    float* logits   = out;                                    // 16384*64
    float* scores   = out + (size_t)N_TOK * NEXP;             // 16384*64
    float* weights  = out + 2ull * N_TOK * NEXP;              // 16384*8
    float* indicesF = weights + (size_t)N_TOK * TOPK;         // 16384*8
    float* histF    = indicesF + (size_t)N_TOK * TOPK;        // 64

    gemm_logits_kernel<<<N_TOK / BM, 256, 0, stream>>>(x, W, noise, logits);
    hipMemsetAsync(histF, 0, NEXP * sizeof(float), stream);   // capture-safe
    router_topk_kernel<<<256, 256, 0, stream>>>(logits, sbias, scores, weights,
                                                indicesF, histF);
}